// Round 9
// baseline (257.256 us; speedup 1.0000x reference)
//
#include <hip/hip_runtime.h>
#include <hip/hip_bf16.h>

#define NB 64      // batch
#define NT 64      // time
#define NA 64      // action dim
#define NH 1024    // hidden
#define NE 32      // embodiments
#define K2DIM 2048 // 2H

typedef unsigned short bf16_t;
typedef __attribute__((ext_vector_type(8))) short bf16x8;  // 8 bf16 = 4 VGPRs
typedef __attribute__((ext_vector_type(4))) float f32x4;   // MFMA accumulator

__device__ __forceinline__ bf16_t f32_to_bf16(float f) {
    unsigned int u = __float_as_uint(f);
    u = (u + 0x7FFFu + ((u >> 16) & 1u)) >> 16;   // round-to-nearest-even
    return (bf16_t)u;
}
__device__ __forceinline__ unsigned cvt2(float x, float y) {
    unsigned short a = __builtin_bit_cast(unsigned short, __float2bfloat16(x));
    unsigned short b = __builtin_bit_cast(unsigned short, __float2bfloat16(y));
    return (unsigned)a | ((unsigned)b << 16);
}

// ---------------------------------------------------------------------------
// K1: a_emb = actions @ W1[cat] + b1 (K=64) and sinusoidal PE, fused.
// Writes x = concat(a_emb, pe) as bf16 [B][T][2H]. grid (B, H/64), block 256.
// ---------------------------------------------------------------------------
__global__ __launch_bounds__(256) void k1_embed(
    const float* __restrict__ actions, const float* __restrict__ W1,
    const float* __restrict__ b1, const int* __restrict__ timesteps,
    const int* __restrict__ cat_ids, bf16_t* __restrict__ x)
{
    __shared__ float act[NT][NA];
    __shared__ float pe[64];

    const int b   = blockIdx.x;
    const int c0  = blockIdx.y * 64;
    const int tid = threadIdx.x;
    const int cat = cat_ids[b];
    const float ts = (float)timesteps[b];

    const float* ab = actions + b * (NT * NA);
    #pragma unroll
    for (int p = 0; p < 16; ++p) {
        int idx = tid + p * 256;
        act[idx >> 6][idx & 63] = ab[idx];
    }
    if (tid < 64) {
        const float kfreq = logf(10000.0f) / 512.0f;
        int c = c0 + tid;
        float v;
        if (c < 512) v = sinf(ts * expf(-(float)c * kfreq));
        else         v = cosf(ts * expf(-(float)(c - 512) * kfreq));
        pe[tid] = v;
    }
    __syncthreads();

    const int cc = tid & 63;
    const int c  = c0 + cc;
    const int t0 = tid >> 6;

    float acc[16];
    const float bias = b1[cat * NH + c];
    #pragma unroll
    for (int i = 0; i < 16; ++i) acc[i] = bias;

    const float* Wp = W1 + (size_t)cat * (NA * NH) + c;
    #pragma unroll 8
    for (int k = 0; k < NA; ++k) {
        float w = Wp[(size_t)k * NH];
        #pragma unroll
        for (int i = 0; i < 16; ++i)
            acc[i] = fmaf(act[t0 + 4 * i][k], w, acc[i]);
    }

    bf16_t* xb = x + (size_t)b * (NT * K2DIM);
    const bf16_t pv = f32_to_bf16(pe[cc]);
    #pragma unroll
    for (int i = 0; i < 16; ++i) {
        int t = t0 + 4 * i;
        xb[(size_t)t * K2DIM + c]      = f32_to_bf16(acc[i]);
        xb[(size_t)t * K2DIM + NH + c] = pv;
    }
}

// ---------------------------------------------------------------------------
// LDS-FREE streaming MFMA GEMM. No __shared__, no barriers, pure TLP.
// grid (16, B), block 256 = 4 waves; global wave gw = bx*4+wv in 0..63:
// th = gw&1 (32-row t-half), nt = gw>>1 (32-col n-tile). Wave computes a
// 32t x 32n tile over full K: 2x2 16x16x32 frags, acc = 16 VGPR.
// A-frags: direct bf16 dwordx4 from x (row-major, contiguous 16 B/lane).
// B-frags: 8 stride-NH fp32 scalar loads (lanes 0..15 = 64 B segments,
// L2/L3-served; t-half duplication 2x absorbed by L2) + v_cvt_pk packs.
// MFMA B layout: element j = W[k = kc*64+ks*32+l4*8+j][col] (r3-validated).
// ---------------------------------------------------------------------------
template<int KDIM, bool SWISH, typename OutT>
__global__ __launch_bounds__(256, 4) void gemm_stream(
    const bf16_t* __restrict__ xin, const float* __restrict__ W,
    const float* __restrict__ bias, const int* __restrict__ cat_ids,
    OutT* __restrict__ out)
{
    const int b    = blockIdx.y;
    const int cat  = cat_ids[b];
    const int tid  = threadIdx.x;
    const int lane = tid & 63;
    const int wv   = tid >> 6;          // 0..3
    const int gw   = blockIdx.x * 4 + wv;
    const int th   = gw & 1;            // t half: rows th*32..+31
    const int nt   = gw >> 1;           // n tile: cols nt*32..+31
    const int l15  = lane & 15;
    const int l4   = lane >> 4;

    // A: lane reads x[b][th*32 + m*16 + l15][kc*64 + ks*32 + l4*8 + 0..7]
    const bf16_t* xA0 = xin + ((size_t)b * NT + th * 32 + l15) * KDIM + l4 * 8;
    const bf16_t* xA1 = xA0 + (size_t)16 * KDIM;
    // B: lane element j = W[cat][kc*64 + ks*32 + l4*8 + j][nt*32 + nf*16 + l15]
    const float* Wl = W + (size_t)cat * KDIM * NH
                        + (size_t)(l4 * 8) * NH + nt * 32 + l15;

    f32x4 acc00, acc01, acc10, acc11;   // acc[m][nf]
    {
        float bv0 = bias[(size_t)cat * NH + nt * 32 + l15];
        float bv1 = bias[(size_t)cat * NH + nt * 32 + 16 + l15];
        acc00 = (f32x4){bv0, bv0, bv0, bv0}; acc10 = acc00;
        acc01 = (f32x4){bv1, bv1, bv1, bv1}; acc11 = acc01;
    }

#define BFRAG(dst, kc, ks, nf) do {                                           \
        const float* bj_ = Wl + ((size_t)((kc) * 64 + (ks) * 32)) * NH        \
                              + (nf) * 16;                                    \
        float f0_ = bj_[0 * NH], f1_ = bj_[1 * NH];                           \
        float f2_ = bj_[2 * NH], f3_ = bj_[3 * NH];                           \
        float f4_ = bj_[4 * NH], f5_ = bj_[5 * NH];                           \
        float f6_ = bj_[6 * NH], f7_ = bj_[7 * NH];                           \
        uint4 u_;                                                             \
        u_.x = cvt2(f0_, f1_); u_.y = cvt2(f2_, f3_);                         \
        u_.z = cvt2(f4_, f5_); u_.w = cvt2(f6_, f7_);                         \
        dst = __builtin_bit_cast(bf16x8, u_); } while (0)

    #pragma unroll 2
    for (int kc = 0; kc < KDIM / 64; ++kc) {
        bf16x8 a00 = *(const bf16x8*)(xA0 + kc * 64);        // ks=0, m=0
        bf16x8 a01 = *(const bf16x8*)(xA0 + kc * 64 + 32);   // ks=1, m=0
        bf16x8 a10 = *(const bf16x8*)(xA1 + kc * 64);        // ks=0, m=1
        bf16x8 a11 = *(const bf16x8*)(xA1 + kc * 64 + 32);   // ks=1, m=1
        bf16x8 b00, b01, b10, b11;                           // b[ks][nf]
        BFRAG(b00, kc, 0, 0);
        BFRAG(b01, kc, 0, 1);
        BFRAG(b10, kc, 1, 0);
        BFRAG(b11, kc, 1, 1);
        acc00 = __builtin_amdgcn_mfma_f32_16x16x32_bf16(a00, b00, acc00, 0, 0, 0);
        acc10 = __builtin_amdgcn_mfma_f32_16x16x32_bf16(a10, b00, acc10, 0, 0, 0);
        acc01 = __builtin_amdgcn_mfma_f32_16x16x32_bf16(a00, b01, acc01, 0, 0, 0);
        acc11 = __builtin_amdgcn_mfma_f32_16x16x32_bf16(a10, b01, acc11, 0, 0, 0);
        acc00 = __builtin_amdgcn_mfma_f32_16x16x32_bf16(a01, b10, acc00, 0, 0, 0);
        acc10 = __builtin_amdgcn_mfma_f32_16x16x32_bf16(a11, b10, acc10, 0, 0, 0);
        acc01 = __builtin_amdgcn_mfma_f32_16x16x32_bf16(a01, b11, acc01, 0, 0, 0);
        acc11 = __builtin_amdgcn_mfma_f32_16x16x32_bf16(a11, b11, acc11, 0, 0, 0);
    }
#undef BFRAG

    // epilogue: C/D layout col = lane&15, row = (lane>>4)*4 + reg  [m89/m91]
#define CWRITE(accv, m, nf) do {                                              \
        int col_ = nt * 32 + (nf) * 16 + l15;                                 \
        _Pragma("unroll")                                                     \
        for (int r = 0; r < 4; ++r) {                                         \
            int row_ = th * 32 + (m) * 16 + l4 * 4 + r;                       \
            float h_ = accv[r];                                               \
            if (SWISH) h_ = h_ / (1.0f + __expf(-h_));                        \
            if constexpr (sizeof(OutT) == 2) {                                \
                out[((size_t)b * NT + row_) * NH + col_] =                    \
                    (OutT)f32_to_bf16(h_);                                    \
            } else {                                                          \
                out[((size_t)b * NT + row_) * NH + col_] = h_;                \
            }                                                                 \
        } } while (0)

    CWRITE(acc00, 0, 0);
    CWRITE(acc01, 0, 1);
    CWRITE(acc10, 1, 0);
    CWRITE(acc11, 1, 1);
#undef CWRITE
}

extern "C" void kernel_launch(void* const* d_in, const int* in_sizes, int n_in,
                              void* d_out, int out_size, void* d_ws, size_t ws_size,
                              hipStream_t stream) {
    const float* actions   = (const float*)d_in[0];
    const float* W1        = (const float*)d_in[1];
    const float* b1        = (const float*)d_in[2];
    const float* W2        = (const float*)d_in[3];
    const float* b2        = (const float*)d_in[4];
    const float* W3        = (const float*)d_in[5];
    const float* b3        = (const float*)d_in[6];
    const int*   timesteps = (const int*)d_in[7];
    const int*   cat_ids   = (const int*)d_in[8];
    float* out = (float*)d_out;

    // ws: x bf16 [B][T][2H] (16.8 MB) then y bf16 [B][T][H] (8.4 MB)
    bf16_t* x = (bf16_t*)d_ws;
    bf16_t* y = x + (size_t)NB * NT * K2DIM;

    k1_embed<<<dim3(NB, NH / 64), 256, 0, stream>>>(actions, W1, b1, timesteps, cat_ids, x);
    gemm_stream<K2DIM, true,  bf16_t><<<dim3(16, NB), 256, 0, stream>>>(x, W2, b2, cat_ids, y);
    gemm_stream<NH,    false, float ><<<dim3(16, NB), 256, 0, stream>>>(y, W3, b3, cat_ids, out);
}

// Round 10
// 176.461 us; speedup vs baseline: 1.4579x; 1.4579x over previous
//
#include <hip/hip_runtime.h>
#include <hip/hip_bf16.h>

#define NB 64      // batch
#define NT 64      // time
#define NA 64      // action dim
#define NH 1024    // hidden
#define NE 32      // embodiments
#define K2DIM 2048 // 2H

typedef unsigned short bf16_t;
typedef __attribute__((ext_vector_type(8))) short bf16x8;  // 8 bf16 = 4 VGPRs
typedef __attribute__((ext_vector_type(4))) short s16x4;   // 4 bf16 = 2 VGPRs
typedef __attribute__((ext_vector_type(4))) float f32x4;   // MFMA accumulator

__device__ __forceinline__ bf16_t f32_to_bf16(float f) {
    unsigned int u = __float_as_uint(f);
    u = (u + 0x7FFFu + ((u >> 16) & 1u)) >> 16;   // round-to-nearest-even
    return (bf16_t)u;
}
__device__ __forceinline__ unsigned cvt2(float x, float y) {
    unsigned short a = __builtin_bit_cast(unsigned short, __float2bfloat16(x));
    unsigned short b = __builtin_bit_cast(unsigned short, __float2bfloat16(y));
    return (unsigned)a | ((unsigned)b << 16);
}

// ---------------------------------------------------------------------------
// Scheduler: group batches by cat (groups of <=4). groups[g*8] = {cat, nb,
// b0..b3 (padded w/ b0)}; nb==0 -> inactive. Actives are a contiguous prefix.
// (verbatim r4 version — correctness-validated in rounds 4/5/7)
// ---------------------------------------------------------------------------
__global__ void make_groups(const int* __restrict__ cat_ids,
                            int* __restrict__ groups)
{
    __shared__ int keys[NB], order[NB], catv[NB];
    __shared__ int gcat[NB], gnb[NB], gb[NB][4];
    __shared__ int sng;

    const int tid = threadIdx.x;   // 0..63
    int c = cat_ids[tid];
    catv[tid] = c;
    keys[tid] = c * 64 + tid;      // unique key, stable within cat
    __syncthreads();

    int mykey = keys[tid];
    int rank = 0;
    for (int j = 0; j < NB; ++j) rank += (keys[j] < mykey) ? 1 : 0;
    order[rank] = tid;
    __syncthreads();

    if (tid == 0) {
        int ng = 0, prev = -1, cnt = 4;
        for (int i = 0; i < NB; ++i) {
            int b  = order[i];
            int cb = catv[b];
            if (cb != prev || cnt == 4) {
                gcat[ng] = cb; gnb[ng] = 0; cnt = 0; prev = cb; ++ng;
            }
            gb[ng - 1][cnt] = b;
            ++cnt; gnb[ng - 1] = cnt;
        }
        sng = ng;
    }
    __syncthreads();

    int ng = sng;
    int base = tid * 8;
    if (tid < ng) {
        int nbv = gnb[tid];
        groups[base + 0] = gcat[tid];
        groups[base + 1] = nbv;
        #pragma unroll
        for (int s = 0; s < 4; ++s)
            groups[base + 2 + s] = gb[tid][s < nbv ? s : 0];  // pad w/ b0
        groups[base + 6] = 0; groups[base + 7] = 0;
    } else {
        #pragma unroll
        for (int s = 0; s < 8; ++s) groups[base + s] = 0;     // nb = 0
    }
}

// ---------------------------------------------------------------------------
// K1: a_emb = actions @ W1[cat] + b1 (K=64) and sinusoidal PE, fused.
// Writes x = concat(a_emb, pe) as bf16 [B][T][2H]. grid (B, H/64), block 256.
// ---------------------------------------------------------------------------
__global__ __launch_bounds__(256) void k1_embed(
    const float* __restrict__ actions, const float* __restrict__ W1,
    const float* __restrict__ b1, const int* __restrict__ timesteps,
    const int* __restrict__ cat_ids, bf16_t* __restrict__ x)
{
    __shared__ float act[NT][NA];
    __shared__ float pe[64];

    const int b   = blockIdx.x;
    const int c0  = blockIdx.y * 64;
    const int tid = threadIdx.x;
    const int cat = cat_ids[b];
    const float ts = (float)timesteps[b];

    const float* ab = actions + b * (NT * NA);
    #pragma unroll
    for (int p = 0; p < 16; ++p) {
        int idx = tid + p * 256;
        act[idx >> 6][idx & 63] = ab[idx];
    }
    if (tid < 64) {
        const float kfreq = logf(10000.0f) / 512.0f;
        int c = c0 + tid;
        float v;
        if (c < 512) v = sinf(ts * expf(-(float)c * kfreq));
        else         v = cosf(ts * expf(-(float)(c - 512) * kfreq));
        pe[tid] = v;
    }
    __syncthreads();

    const int cc = tid & 63;
    const int c  = c0 + cc;
    const int t0 = tid >> 6;

    float acc[16];
    const float bias = b1[cat * NH + c];
    #pragma unroll
    for (int i = 0; i < 16; ++i) acc[i] = bias;

    const float* Wp = W1 + (size_t)cat * (NA * NH) + c;
    #pragma unroll 8
    for (int k = 0; k < NA; ++k) {
        float w = Wp[(size_t)k * NH];
        #pragma unroll
        for (int i = 0; i < 16; ++i)
            acc[i] = fmaf(act[t0 + 4 * i][k], w, acc[i]);
    }

    bf16_t* xb = x + (size_t)b * (NT * K2DIM);
    const bf16_t pv = f32_to_bf16(pe[cc]);
    #pragma unroll
    for (int i = 0; i < 16; ++i) {
        int t = t0 + 4 * i;
        xb[(size_t)t * K2DIM + c]      = f32_to_bf16(acc[i]);
        xb[(size_t)t * K2DIM + NH + c] = pv;
    }
}

// ---------------------------------------------------------------------------
// W-stream grouped MFMA GEMM. Block = (group of <=4 same-cat batches, 64 n).
// grid (16 n [x-major], 64 groups) -> ~470 active blocks, contiguous prefix.
// 256 thr = 4 waves; wave wv owns batch-slot wv: tile 64t x 64n = 4m x 4nf
// frags (acc 64 VGPR). W is the ONLY LDS-staged operand (transpose required):
// K-chunk 64 x 64n fp32 -> bf16 subtiled [k/4][n/16][4][16], double-buffered
// 2 x 8 KB; staging writes are contiguous 1 KB per wave (zero conflicts).
// A-frags read DIRECTLY from global x (16-B contiguous per lane, L1/L2).
// B-frags via ds_read_b64_tr_b16 (byte-identical to r4/r5-validated maps).
// Pipeline: named-reg W queue lead-2 (qa/qb); per chunk: WSQ (write W c) ->
// ALD (A-frags c) -> sched_barrier -> WLQ (W c+2) -> lgkmcnt(0) ->
// raw s_barrier -> CMP (tr-reads + 32 MFMA). In-order vmcnt: MFMA's A-wait
// = vmcnt(4), leaving the 4 WLQ loads of chunk c+2 in flight (never drained).
// ---------------------------------------------------------------------------
template<int KDIM, bool SWISH, typename OutT>
__global__ __launch_bounds__(256) void gemm_wstream(
    const bf16_t* __restrict__ xin, const float* __restrict__ W,
    const float* __restrict__ bias, const int* __restrict__ groups,
    OutT* __restrict__ out)
{
    __shared__ __align__(128) char wlds[2][8192];   // 16 KB

    const int* grp = groups + blockIdx.y * 8;
    const int mult = grp[1];
    if (mult == 0) return;
    const int cat = grp[0];

    const int n0   = blockIdx.x * 64;
    const int tid  = threadIdx.x;
    const int lane = tid & 63;
    const int wv   = tid >> 6;          // 0..3 = batch slot
    const int l15  = lane & 15;
    const int l4   = lane >> 4;
    const int myb  = grp[2 + wv];       // padded with b0 for wv >= mult

    constexpr int NCH = KDIM / 64;

    // --- W staging: thread -> (k rows wk0, wk0+32; n-oct wo8) ---
    const int wo8 = tid & 7;            // n = wo8*8
    const int wk0 = tid >> 3;           // 0..31
    const float* wg = W + (size_t)cat * KDIM * NH + (size_t)wk0 * NH + n0 + wo8 * 8;
    // subtile byte addr: (k>>2)*512 + (n16)*128 + (k&3)*32 + (oct&1)*16
    const int wl0 = ((wk0 >> 2) * 512) + ((wo8 >> 1) * 128)
                  + ((wk0 & 3) * 32) + ((wo8 & 1) * 16);   // row wk0+32: +4096

    // --- A base: x[myb][m*16 + l15][c*64 + ks*32 + l4*8 + 0..7] ---
    const bf16_t* xa = xin + ((size_t)myb * NT + l15) * KDIM + l4 * 8;

    f32x4 acc[4][4];
    #pragma unroll
    for (int nf = 0; nf < 4; ++nf) {
        float bv = bias[(size_t)cat * NH + n0 + nf * 16 + l15];
        #pragma unroll
        for (int m = 0; m < 4; ++m) acc[m][nf] = (f32x4){bv, bv, bv, bv};
    }

    const unsigned lbase = (unsigned)(unsigned long long)&wlds[0][0];
    const unsigned trb   = lbase + (unsigned)(l4 * 1024 + l15 * 8);

    // named prefetch queue + named A-frags (rule #20: no arrays)
    float4 qa0, qa1, qa2, qa3, qb0, qb1, qb2, qb3;
    bf16x8 a0s0, a1s0, a2s0, a3s0, a0s1, a1s1, a2s1, a3s1;

#define WLQ(r0, r1, r2, r3, c) do { int i_ = (c) < NCH ? (c) : NCH - 1;       \
        const float* s_ = wg + (size_t)i_ * 64 * NH;                          \
        r0 = *(const float4*)(s_);                                            \
        r1 = *(const float4*)(s_ + 4);                                        \
        r2 = *(const float4*)(s_ + (size_t)32 * NH);                          \
        r3 = *(const float4*)(s_ + (size_t)32 * NH + 4); } while (0)
#define WSQ(p, r0, r1, r2, r3) do { char* bp_ = &wlds[p][0];                  \
        uint4 u_;                                                             \
        u_.x = cvt2(r0.x, r0.y); u_.y = cvt2(r0.z, r0.w);                     \
        u_.z = cvt2(r1.x, r1.y); u_.w = cvt2(r1.z, r1.w);                     \
        *(uint4*)(bp_ + wl0) = u_;                                            \
        u_.x = cvt2(r2.x, r2.y); u_.y = cvt2(r2.z, r2.w);                     \
        u_.z = cvt2(r3.x, r3.y); u_.w = cvt2(r3.z, r3.w);                     \
        *(uint4*)(bp_ + wl0 + 4096) = u_; } while (0)
#define ALD(c) do { const bf16_t* s_ = xa + (size_t)(c) * 64;                 \
        a0s0 = *(const bf16x8*)(s_);                                          \
        a1s0 = *(const bf16x8*)(s_ + (size_t)16 * KDIM);                      \
        a2s0 = *(const bf16x8*)(s_ + (size_t)32 * KDIM);                      \
        a3s0 = *(const bf16x8*)(s_ + (size_t)48 * KDIM);                      \
        a0s1 = *(const bf16x8*)(s_ + 32);                                     \
        a1s1 = *(const bf16x8*)(s_ + (size_t)16 * KDIM + 32);                 \
        a2s1 = *(const bf16x8*)(s_ + (size_t)32 * KDIM + 32);                 \
        a3s1 = *(const bf16x8*)(s_ + (size_t)48 * KDIM + 32); } while (0)
#define MF(d, A, B) d = __builtin_amdgcn_mfma_f32_16x16x32_bf16(A, B, d, 0, 0, 0)
#define TRPAIR(lo_, hi_, addr_, off_) do {                                    \
        asm volatile("ds_read_b64_tr_b16 %0, %1 offset:" #off_               \
                     : "=v"(lo_) : "v"(addr_));                               \
        asm volatile("ds_read_b64_tr_b16 %0, %1 offset:" #off_ "+512"        \
                     : "=v"(hi_) : "v"(addr_)); } while (0)
#define CMP(p) do {                                                           \
        unsigned ab_ = trb + (p) * 8192u;                                     \
        s16x4 lo0, hi0, lo1, hi1, lo2, hi2, lo3, hi3;                         \
        TRPAIR(lo0, hi0, ab_, 0);                                             \
        TRPAIR(lo1, hi1, ab_, 128);                                           \
        TRPAIR(lo2, hi2, ab_, 256);                                           \
        TRPAIR(lo3, hi3, ab_, 384);                                           \
        asm volatile("s_waitcnt lgkmcnt(0)" ::: "memory");                    \
        __builtin_amdgcn_sched_barrier(0);                                    \
        {   bf16x8 b0 = __builtin_shufflevector(lo0, hi0, 0,1,2,3,4,5,6,7);   \
            bf16x8 b1 = __builtin_shufflevector(lo1, hi1, 0,1,2,3,4,5,6,7);   \
            bf16x8 b2 = __builtin_shufflevector(lo2, hi2, 0,1,2,3,4,5,6,7);   \
            bf16x8 b3 = __builtin_shufflevector(lo3, hi3, 0,1,2,3,4,5,6,7);   \
            MF(acc[0][0], a0s0, b0); MF(acc[1][0], a1s0, b0);                 \
            MF(acc[2][0], a2s0, b0); MF(acc[3][0], a3s0, b0);                 \
            MF(acc[0][1], a0s0, b1); MF(acc[1][1], a1s0, b1);                 \
            MF(acc[2][1], a2s0, b1); MF(acc[3][1], a3s0, b1);                 \
            MF(acc[0][2], a0s0, b2); MF(acc[1][2], a1s0, b2);                 \
            MF(acc[2][2], a2s0, b2); MF(acc[3][2], a3s0, b2);                 \
            MF(acc[0][3], a0s0, b3); MF(acc[1][3], a1s0, b3);                 \
            MF(acc[2][3], a2s0, b3); MF(acc[3][3], a3s0, b3); }               \
        unsigned ab2_ = ab_ + 4096u;                                          \
        TRPAIR(lo0, hi0, ab2_, 0);                                            \
        TRPAIR(lo1, hi1, ab2_, 128);                                          \
        TRPAIR(lo2, hi2, ab2_, 256);                                          \
        TRPAIR(lo3, hi3, ab2_, 384);                                          \
        asm volatile("s_waitcnt lgkmcnt(0)" ::: "memory");                    \
        __builtin_amdgcn_sched_barrier(0);                                    \
        {   bf16x8 b0 = __builtin_shufflevector(lo0, hi0, 0,1,2,3,4,5,6,7);   \
            bf16x8 b1 = __builtin_shufflevector(lo1, hi1, 0,1,2,3,4,5,6,7);   \
            bf16x8 b2 = __builtin_shufflevector(lo2, hi2, 0,1,2,3,4,5,6,7);   \
            bf16x8 b3 = __builtin_shufflevector(lo3, hi3, 0,1,2,3,4,5,6,7);   \
            MF(acc[0][0], a0s1, b0); MF(acc[1][0], a1s1, b0);                 \
            MF(acc[2][0], a2s1, b0); MF(acc[3][0], a3s1, b0);                 \
            MF(acc[0][1], a0s1, b1); MF(acc[1][1], a1s1, b1);                 \
            MF(acc[2][1], a2s1, b1); MF(acc[3][1], a3s1, b1);                 \
            MF(acc[0][2], a0s1, b2); MF(acc[1][2], a1s1, b2);                 \
            MF(acc[2][2], a2s1, b2); MF(acc[3][2], a3s1, b2);                 \
            MF(acc[0][3], a0s1, b3); MF(acc[1][3], a1s1, b3);                 \
            MF(acc[2][3], a2s1, b3); MF(acc[3][3], a3s1, b3); }               \
    } while (0)

    // prologue: queue qa<-chunk0, qb<-chunk1 (lead-2 established in-loop)
    WLQ(qa0, qa1, qa2, qa3, 0);
    WLQ(qb0, qb1, qb2, qb3, 1);

    for (int kc = 0; kc < NCH; kc += 2) {
        // chunk kc (buffer 0)
        WSQ(0, qa0, qa1, qa2, qa3);          // auto vmcnt(4): qa old, qb in flight
        ALD(kc);                             // A-frags BEFORE refill (vmcnt order)
        __builtin_amdgcn_sched_barrier(0);
        WLQ(qa0, qa1, qa2, qa3, kc + 2);     // stays in flight through CMP
        asm volatile("s_waitcnt lgkmcnt(0)" ::: "memory");  // ds_writes visible
        __builtin_amdgcn_s_barrier();
        CMP(0);                              // MFMA A-wait = vmcnt(4), qa survives
        // chunk kc+1 (buffer 1)
        WSQ(1, qb0, qb1, qb2, qb3);
        ALD(kc + 1);
        __builtin_amdgcn_sched_barrier(0);
        WLQ(qb0, qb1, qb2, qb3, kc + 3);
        asm volatile("s_waitcnt lgkmcnt(0)" ::: "memory");
        __builtin_amdgcn_s_barrier();
        CMP(1);
    }
#undef WLQ
#undef WSQ
#undef ALD
#undef MF
#undef TRPAIR
#undef CMP

    // epilogue: C/D layout col = lane&15, row = (lane>>4)*4 + reg  [m89/m91]
    if (wv < mult) {
        #pragma unroll
        for (int m = 0; m < 4; ++m) {
            #pragma unroll
            for (int nf = 0; nf < 4; ++nf) {
                int col = n0 + nf * 16 + l15;
                #pragma unroll
                for (int r = 0; r < 4; ++r) {
                    int row = m * 16 + l4 * 4 + r;
                    float h = acc[m][nf][r];
                    if (SWISH) h = h / (1.0f + __expf(-h));
                    if constexpr (sizeof(OutT) == 2) {
                        out[((size_t)myb * NT + row) * NH + col] = (OutT)f32_to_bf16(h);
                    } else {
                        out[((size_t)myb * NT + row) * NH + col] = h;
                    }
                }
            }
        }
    }
}

extern "C" void kernel_launch(void* const* d_in, const int* in_sizes, int n_in,
                              void* d_out, int out_size, void* d_ws, size_t ws_size,
                              hipStream_t stream) {
    const float* actions   = (const float*)d_in[0];
    const float* W1        = (const float*)d_in[1];
    const float* b1        = (const float*)d_in[2];
    const float* W2        = (const float*)d_in[3];
    const float* b2        = (const float*)d_in[4];
    const float* W3        = (const float*)d_in[5];
    const float* b3        = (const float*)d_in[6];
    const int*   timesteps = (const int*)d_in[7];
    const int*   cat_ids   = (const int*)d_in[8];
    float* out = (float*)d_out;

    // ws: x bf16 [B][T][2H] (16.8 MB), y bf16 [B][T][H] (8.4 MB), groups (2 KB)
    bf16_t* x = (bf16_t*)d_ws;
    bf16_t* y = x + (size_t)NB * NT * K2DIM;
    int* groups = (int*)(y + (size_t)NB * NT * NH);

    make_groups<<<1, 64, 0, stream>>>(cat_ids, groups);
    k1_embed<<<dim3(NB, NH / 64), 256, 0, stream>>>(actions, W1, b1, timesteps, cat_ids, x);
    gemm_wstream<K2DIM, true,  bf16_t><<<dim3(16, 64), 256, 0, stream>>>(x, W2, b2, groups, y);
    gemm_wstream<NH,    false, float ><<<dim3(16, 64), 256, 0, stream>>>(y, W3, b3, groups, out);
}